// Round 19
// baseline (96.296 us; speedup 1.0000x reference)
//
#include <hip/hip_runtime.h>
#include <hip/hip_bf16.h>

// ChannelDeAttention: B=64,S=512,C=256,H=128,P=512
// bf16 MFMA (16x16x32), fp32 accum. 5 launches. XOR-swizzled LDS.
// R19 = R18 with projscore GEMM phase on a BK=32 3-stage counted-vmcnt
// pipeline (96KB bufs aliasing the 128KB q/k region), sc folded into q.

typedef __attribute__((ext_vector_type(8))) short bf16x8;
typedef __attribute__((ext_vector_type(4))) float f32x4;
typedef __attribute__((ext_vector_type(8))) unsigned short ushort8;

typedef __attribute__((address_space(1))) void* as1vp;
typedef __attribute__((address_space(3))) void* as3vp;

__device__ __forceinline__ void gl2lds16(const void* g, void* l) {
  __builtin_amdgcn_global_load_lds((as1vp)(void*)g, (as3vp)l, 16, 0, 0);
}

__device__ __forceinline__ float bf2f(unsigned short u) {
  union { unsigned int i; float f; } v; v.i = ((unsigned int)u) << 16; return v.f;
}
__device__ __forceinline__ unsigned short f2bf(float f) {
  union { float f; unsigned int i; } v; v.f = f;
  unsigned int r = v.i + 0x7FFFu + ((v.i >> 16) & 1u);
  return (unsigned short)(r >> 16);
}
__device__ __forceinline__ unsigned long long pack4bf(float a, float b, float c, float d) {
  return (unsigned long long)f2bf(a) | ((unsigned long long)f2bf(b) << 16) |
         ((unsigned long long)f2bf(c) << 32) | ((unsigned long long)f2bf(d) << 48);
}
// BK=32 swizzle (R12-verified): rows 64B, 4x16B slots, 2 lanes/bank reads (free)
__device__ __forceinline__ int swz32(int row, int s) { return s ^ ((row >> 1) & 3); }

// ------- transposes (x + 5 weight mats) + plain wv cast, one launch -----------------
__global__ void __launch_bounds__(256) tcast_all(
    const float* __restrict__ x,
    const float* __restrict__ wq1, const float* __restrict__ wk1,
    const float* __restrict__ wq2, const float* __restrict__ wk2,
    const float* __restrict__ wq3, const float* __restrict__ wk3,
    const float* __restrict__ wv, const float* __restrict__ wo,
    unsigned short* __restrict__ XT,
    unsigned short* __restrict__ W1, unsigned short* __restrict__ W2,
    unsigned short* __restrict__ W3, unsigned short* __restrict__ WVNT,
    unsigned short* __restrict__ WOT) {
  const int bid = blockIdx.x;
  const int t = threadIdx.x;
  if (bid >= 2168) {  // plain-cast wv to bf16 row-major (coalesced)
    long i0 = (long)(bid - 2168) * 2048 + t * 8;
    f32x4 a = *(const f32x4*)(wv + i0);
    f32x4 b = *(const f32x4*)(wv + i0 + 4);
    ushort8 o;
#pragma unroll
    for (int j = 0; j < 4; ++j) { o[j] = f2bf(a[j]); o[4 + j] = f2bf(b[j]); }
    *(ushort8*)(WVNT + i0) = o;
    return;
  }
  __shared__ float lds[64][68];
  const float* S; unsigned short* D; int R, Cc, r0, c0, rowoff = 0;
  if (bid < 2048) {
    int bz = bid >> 5, i = bid & 31;
    S = x + (long)bz * 131072; D = XT + (long)bz * 131072;
    R = 512; Cc = 256; r0 = (i & 7) * 64; c0 = (i >> 3) * 64;
  } else {
    int wb = bid - 2048;
    if (wb < 32) {
      int m = wb >> 4, i = wb & 15;
      S = m ? wk1 : wq1; D = W1; R = 512; Cc = 128;
      r0 = (i & 7) * 64; c0 = (i >> 3) * 64; rowoff = m * 128;
    } else if (wb < 48) {
      int m = (wb - 32) >> 3, i = (wb - 32) & 7;
      S = m ? wk2 : wq2; D = W2; R = 256; Cc = 128;
      r0 = (i & 3) * 64; c0 = (i >> 2) * 64; rowoff = m * 128;
    } else if (wb < 56) {
      int m = (wb - 48) >> 2, i = (wb - 48) & 3;
      S = m ? wk3 : wq3; D = W3; R = 128; Cc = 128;
      r0 = (i & 1) * 64; c0 = (i >> 1) * 64; rowoff = m * 128;
    } else {
      int i = wb - 56; S = wo; D = WOT; R = 512; Cc = 512;
      r0 = (i & 7) * 64; c0 = (i >> 3) * 64;
    }
  }
  {
    const int row = t >> 2, cq = (t & 3) * 16;
    const float* Sp = S + (long)(r0 + row) * Cc + c0 + cq;
#pragma unroll
    for (int j = 0; j < 4; ++j)
      *(f32x4*)&lds[row][cq + j * 4] = *(const f32x4*)(Sp + j * 4);
  }
  __syncthreads();
  {
    const int rq = (t & 15) * 4, ccb = t >> 4;
#pragma unroll
    for (int j = 0; j < 4; ++j) {
      int cc = ccb + j * 16;
      *(unsigned long long*)(D + (long)(c0 + cc + rowoff) * R + r0 + rq) =
          pack4bf(lds[rq][cc], lds[rq + 1][cc], lds[rq + 2][cc], lds[rq + 3][cc]);
    }
  }
}

// ------- FUSED proj + scores + softmax (+ WVOT + BVO blocks), 1024 threads ----------
// grid (1,1,468): z<448 fused sub-batch; z in [448,464) WVOT; z>=464 BVO.
__global__ void __launch_bounds__(1024) projscore(
    const unsigned short* __restrict__ XT,
    const unsigned short* __restrict__ W1, const unsigned short* __restrict__ W2,
    const unsigned short* __restrict__ W3,
    const unsigned short* __restrict__ WOT, const unsigned short* __restrict__ WVNT,
    unsigned short* __restrict__ WVOT, float* __restrict__ BVO,
    const float* __restrict__ bv,
    unsigned short* __restrict__ A1F, unsigned short* __restrict__ A2F,
    unsigned short* __restrict__ A3F,
    const float* __restrict__ bq1, const float* __restrict__ bk1,
    const float* __restrict__ bq2, const float* __restrict__ bk2,
    const float* __restrict__ bq3, const float* __restrict__ bk3) {
  extern __shared__ char smem[];
  const int z = blockIdx.z;
  const int t = threadIdx.x, lane = t & 63, wid = t >> 6;  // wid 0..15

  if (z >= 464) {  // ---- BVO[p] = sum_s bv[s] * WOT[p][s]; 16 waves x 8 p
    int p0 = (z - 464) * 128 + wid * 8;
    f32x4 b0 = *(const f32x4*)(bv + lane * 8);
    f32x4 b1 = *(const f32x4*)(bv + lane * 8 + 4);
#pragma unroll
    for (int i = 0; i < 8; ++i) {
      int p = p0 + i;
      bf16x8 wrow = *(const bf16x8*)(WOT + (long)p * 512 + lane * 8);
      float s = 0.0f;
#pragma unroll
      for (int j = 0; j < 4; ++j) {
        s += b0[j] * bf2f((unsigned short)wrow[j]);
        s += b1[j] * bf2f((unsigned short)wrow[4 + j]);
      }
#pragma unroll
      for (int off = 1; off < 64; off <<= 1) s += __shfl_xor(s, off, 64);
      if (lane == 0) BVO[p] = s;
    }
    return;
  }

  const int rS8 = t >> 3, sS8 = t & 7;  // 128 rows x 8 slots (BK=64 staging, WVOT)
  const int rS4 = t >> 2, sS4 = t & 3;  // 256 rows x 4 slots (BK=32 staging, fused)

  if (z >= 448) {  // ---- WVOT[p][s], SQ128 tile, 16 waves (32x32 wave-tile), single-buf
    const int w = z - 448;
    const int m0 = (w >> 2) * 128, n0 = (w & 3) * 128;
    const unsigned short* Ab = WOT + (long)m0 * 512;
    const unsigned short* Bb = WVNT + (long)n0 * 512;
    const int wmb = (wid >> 2) * 32, wnb = (wid & 3) * 32;
    f32x4 acc[2][2] = {};
    for (int k0 = 0; k0 < 512; k0 += 64) {
      int sc = (sS8 ^ (rS8 & 7)) * 8;
      gl2lds16(Ab + (long)rS8 * 512 + k0 + sc, smem + t * 16);
      gl2lds16(Bb + (long)rS8 * 512 + k0 + sc, smem + 16384 + t * 16);
      __syncthreads();
#pragma unroll
      for (int kk = 0; kk < 2; ++kk) {
        const int slot = kk * 4 + (lane >> 4);
        bf16x8 af[2], bfr[2];
#pragma unroll
        for (int mi = 0; mi < 2; ++mi) {
          int row = wmb + mi * 16 + (lane & 15);
          af[mi] = *(const bf16x8*)(smem + row * 128 + 16 * (slot ^ (row & 7)));
        }
#pragma unroll
        for (int ni = 0; ni < 2; ++ni) {
          int row = wnb + ni * 16 + (lane & 15);
          bfr[ni] = *(const bf16x8*)(smem + 16384 + row * 128 + 16 * (slot ^ (row & 7)));
        }
#pragma unroll
        for (int mi = 0; mi < 2; ++mi)
#pragma unroll
          for (int ni = 0; ni < 2; ++ni)
            acc[mi][ni] = __builtin_amdgcn_mfma_f32_16x16x32_bf16(af[mi], bfr[ni], acc[mi][ni], 0, 0, 0);
      }
      __syncthreads();
    }
#pragma unroll
    for (int ni = 0; ni < 2; ++ni) {
      int col = n0 + wnb + ni * 16 + (lane & 15);
#pragma unroll
      for (int mi = 0; mi < 2; ++mi) {
        int rowb = m0 + wmb + mi * 16 + (lane >> 4) * 4;
#pragma unroll
        for (int r = 0; r < 4; ++r)
          WVOT[(long)(rowb + r) * 512 + col] = f2bf(acc[mi][ni][r]);
      }
    }
    return;
  }

  // ---- fused path: GEMM (BM=256 x BN=256 q|k), BK=32, 3-stage counted pipeline ----
  const unsigned short* Ab; const unsigned short* Bw; unsigned short* AF;
  const float *bq, *bk; int K; long sb;
  if (z < 64) {
    K = 512; Bw = W1; AF = A1F; sb = z; bq = bq1; bk = bk1;
    Ab = XT + (long)z * 131072;
  } else if (z < 192) {
    int u = z - 64; K = 256; Bw = W2; AF = A2F; sb = u; bq = bq2; bk = bk2;
    Ab = XT + (long)(u >> 1) * 131072 + (u & 1) * 256;
  } else {
    int u = z - 192; K = 128; Bw = W3; AF = A3F; sb = u; bq = bq3; bk = bk3;
    Ab = XT + (long)(u >> 2) * 131072 + (u & 3) * 128;
  }
  const int wmb = (wid >> 2) * 64, wnb = (wid & 3) * 64;  // 4m x 4n waves

  // stage buf (32KB): A[256][32]sw at 0, B[256][32]sw at 16K. 2 loads/thread.
  auto stage = [&](int buf, int k0) {
    char* s = smem + buf * 32768;
    int sc = swz32(rS4, sS4) * 8;
    gl2lds16(Ab + (long)rS4 * 512 + k0 + sc, s + t * 16);
    gl2lds16(Bw + (long)rS4 * K + k0 + sc, s + 16384 + t * 16);
  };

  f32x4 acc[4][4] = {};
  const int nst = K >> 5;
  stage(0, 0);
  stage(1, 32);
  for (int j = 0; j < nst; ++j) {
    if (j + 1 < nst) asm volatile("s_waitcnt vmcnt(2)" ::: "memory");
    else             asm volatile("s_waitcnt vmcnt(0)" ::: "memory");
    __builtin_amdgcn_s_barrier();
    if (j + 2 < nst) stage((j + 2) % 3, (j + 2) * 32);
    const char* s = smem + (j % 3) * 32768;
    const int kb = lane >> 4;
    bf16x8 af[4], bfr[4];
#pragma unroll
    for (int mi = 0; mi < 4; ++mi) {
      int row = wmb + mi * 16 + (lane & 15);
      af[mi] = *(const bf16x8*)(s + row * 64 + (swz32(row, kb) << 4));
    }
#pragma unroll
    for (int ni = 0; ni < 4; ++ni) {
      int row = wnb + ni * 16 + (lane & 15);
      bfr[ni] = *(const bf16x8*)(s + 16384 + row * 64 + (swz32(row, kb) << 4));
    }
    // swapped operands: lane holds 4 consecutive out-cols per fragment
#pragma unroll
    for (int mi = 0; mi < 4; ++mi)
#pragma unroll
      for (int ni = 0; ni < 4; ++ni)
        acc[mi][ni] = __builtin_amdgcn_mfma_f32_16x16x32_bf16(bfr[ni], af[mi], acc[mi][ni], 0, 0, 0);
  }
  __syncthreads();  // all reads of stage bufs done before q/k overwrite

  // write q/k into swizzled LDS: q @ [2chunks][256][64] at 0, k at 65536.
  // q (and its bias) pre-scaled by 1/sqrt(128) so softmax skips the mul.
  {
    const bool isQ = (wnb < 128);
    const float qsc = isQ ? 0.088388347648318447f : 1.0f;
    const int chB = isQ ? 0 : 65536;
    const float* bias = isQ ? bq : bk;
    const int hbase = wnb & 127;
#pragma unroll
    for (int mi = 0; mi < 4; ++mi) {
      int rowm = wmb + mi * 16 + (lane & 15);
#pragma unroll
      for (int ni = 0; ni < 4; ++ni) {
        int h = hbase + ni * 16 + (lane >> 4) * 4;
        int addr = chB + (h >> 6) * 32768 + rowm * 128 +
                   16 * (((h & 63) >> 3) ^ (rowm & 7)) + (h & 7) * 2;
        *(unsigned long long*)(smem + addr) =
            pack4bf((acc[mi][ni][0] + bias[h]) * qsc, (acc[mi][ni][1] + bias[h + 1]) * qsc,
                    (acc[mi][ni][2] + bias[h + 2]) * qsc, (acc[mi][ni][3] + bias[h + 3]) * qsc);
      }
    }
  }
  __syncthreads();

  // scores: S = q k^T (pre-scaled), wave w -> q-rows [w*16, w*16+16)
  f32x4 acc2[16] = {};
  const int qrow = wid * 16 + (lane & 15);
#pragma unroll
  for (int kc = 0; kc < 2; ++kc)
#pragma unroll
    for (int kk = 0; kk < 2; ++kk) {
      const int slot = kk * 4 + (lane >> 4);
      bf16x8 qf = *(const bf16x8*)(smem + kc * 32768 + qrow * 128 + 16 * (slot ^ (qrow & 7)));
#pragma unroll
      for (int ni = 0; ni < 16; ++ni) {
        int krow = ni * 16 + (lane & 15);
        bf16x8 kf = *(const bf16x8*)(smem + 65536 + kc * 32768 + krow * 128 + 16 * (slot ^ (krow & 7)));
        acc2[ni] = __builtin_amdgcn_mfma_f32_16x16x32_bf16(qf, kf, acc2[ni], 0, 0, 0);
      }
    }

  {
    int m0idx = wid >> 2, quad = wid & 3;
    unsigned short* Of = AF + ((sb * 4 + m0idx) * 256 + quad * 64 + lane) * 64;
#pragma unroll
    for (int r = 0; r < 4; ++r) {
      float mx = -1e30f;
#pragma unroll
      for (int ni = 0; ni < 16; ++ni) mx = fmaxf(mx, acc2[ni][r]);
#pragma unroll
      for (int off = 1; off < 16; off <<= 1) mx = fmaxf(mx, __shfl_xor(mx, off, 64));
      float s = 0.0f;
#pragma unroll
      for (int ni = 0; ni < 16; ++ni) {
        float p = __expf(acc2[ni][r] - mx);
        acc2[ni][r] = p;
        s += p;
      }
#pragma unroll
      for (int off = 1; off < 16; off <<= 1) s += __shfl_xor(s, off, 64);
      float inv = 1.0f / s;
      ushort8 lo, hi;
#pragma unroll
      for (int j = 0; j < 8; ++j) {
        lo[j] = f2bf(acc2[j][r] * inv);
        hi[j] = f2bf(acc2[8 + j][r] * inv);
      }
      *(ushort8*)(Of + r * 16) = lo;
      *(ushort8*)(Of + r * 16 + 8) = hi;
    }
  }
}

// ------- gate: flat elementwise in fragment space, coalesced reads ------------------
__global__ void __launch_bounds__(256) gate_frag(
    const unsigned short* __restrict__ A1F, const unsigned short* __restrict__ A2F,
    const unsigned short* __restrict__ A3F, unsigned short* __restrict__ ATTN) {
  const long gid = (long)blockIdx.x * 256 + threadIdx.x;
  const long i = gid * 8;
  const int b = (int)(i >> 16);
  const int rest = (int)(i & 65535);
  ushort8 a1 = *(const ushort8*)(A1F + i);
  const long i2 = ((long)(2 * b) << 16) + rest;
  ushort8 a2a = *(const ushort8*)(A2F + i2);
  ushort8 a2b = *(const ushort8*)(A2F + i2 + 65536);
  const long i3 = ((long)(4 * b) << 16) + rest;
  ushort8 a3a = *(const ushort8*)(A3F + i3);
  ushort8 a3b = *(const ushort8*)(A3F + i3 + 65536);
  ushort8 a3c = *(const ushort8*)(A3F + i3 + 131072);
  ushort8 a3d = *(const ushort8*)(A3F + i3 + 196608);
  const int f = rest & 63;
  const int tl = (rest >> 6) & 255;
  const int m0idx = rest >> 14;
  const int quad = (tl >> 6) & 3;
  const int lane_s = tl & 63;
  const int r = f >> 4;
  const int u0 = f & 15;  // 0 or 8
  const int row = m0idx * 64 + quad * 16 + (lane_s >> 4) * 4 + r;
  unsigned short* Orow = ATTN + ((long)b << 16) + (long)row * 256 + (lane_s & 15);
#pragma unroll
  for (int j = 0; j < 8; ++j) {
    float A1 = bf2f(a1[j]);
    float A2 = 0.5f * (bf2f(a2a[j]) + bf2f(a2b[j]));
    float A3 = 0.25f * (bf2f(a3a[j]) + bf2f(a3b[j]) + bf2f(a3c[j]) + bf2f(a3d[j]));
    float m = fmaxf(A1, fmaxf(A2, A3));
    float e1 = __expf(A1 - m), e2 = __expf(A2 - m), e3 = __expf(A3 - m);
    Orow[(u0 + j) * 16] = f2bf((A1 * e1 + A2 * e2 + A3 * e3) / (e1 + e2 + e3));
  }
}

// ------- 8-wave TALL(256x128) NT GEMM, 3-stage pipeline, counted vmcnt (R16) --------
template <int F32OUT, int BIASMODE>
__global__ void __launch_bounds__(512) gemm8(
    const unsigned short* __restrict__ A, const unsigned short* __restrict__ B,
    void* __restrict__ OutV, const float* __restrict__ bias,
    int lda, int ldb, int K, long astr, long bstr, long ostr, int ldo) {
  extern __shared__ char smem[];  // per buf 48K: A [256][64]sw + B [128][64]sw
  const int t = threadIdx.x, lane = t & 63, wid = t >> 6;
  const int wmb = (wid >> 1) * 64, wnb = (wid & 1) * 64;
  const int m0 = blockIdx.y * 256, n0 = blockIdx.x * 128;
  const int bz = blockIdx.z;
  const unsigned short* Ab = A + (long)bz * astr + (long)m0 * lda;
  const unsigned short* Bb = B + (long)bz * bstr + (long)n0 * ldb;
  const int srow = t >> 3, ssl = t & 7;

  auto stage = [&](int buf, int k0) {  // 6 loads/thread
    char* s = smem + buf * 49152;
#pragma unroll
    for (int i = 0; i < 4; ++i) {
      int row = i * 64 + srow;
      gl2lds16(Ab + (long)row * lda + k0 + (ssl ^ (row & 7)) * 8, s + i * 8192 + t * 16);
    }
#pragma unroll
    for (int i = 0; i < 2; ++i) {
      int row = i * 64 + srow;
      gl2lds16(Bb + (long)row * ldb + k0 + (ssl ^ (row & 7)) * 8,
               s + 32768 + i * 8192 + t * 16);
    }
  };

  f32x4 acc[4][4] = {};
  const int nst = K >> 6;
  stage(0, 0);
  stage(1, 64);
  for (int j = 0; j < nst; ++j) {
    if (j + 1 < nst) asm volatile("s_waitcnt vmcnt(6)" ::: "memory");
    else             asm volatile("s_waitcnt vmcnt(0)" ::: "memory");
    __builtin_amdgcn_s_barrier();
    if (j + 2 < nst) stage((j + 2) % 3, (j + 2) * 64);
    const char* s = smem + (j % 3) * 49152;
#pragma unroll
    for (int kk = 0; kk < 2; ++kk) {
      const int slot = kk * 4 + (lane >> 4);
      bf16x8 af[4], bfr[4];
#pragma unroll
      for (int mi = 0; mi < 4; ++mi) {
        int row = wmb + mi * 16 + (lane & 15);
        af[mi] = *(const bf16x8*)(s + row * 128 + 16 * (slot ^ (row & 7)));
      }
#pragma unroll
      for (int ni = 0; ni < 4; ++ni) {
        int row = wnb + ni * 16 + (lane & 15);
        bfr[ni] = *(const bf16x8*)(s + 32768 + row * 128 + 16 * (slot ^ (row & 7)));
      }
#pragma unroll
      for (int mi = 0; mi < 4; ++mi)
#pragma unroll
        for (int ni = 0; ni < 4; ++ni)
          acc[mi][ni] = __builtin_amdgcn_mfma_f32_16x16x32_bf16(af[mi], bfr[ni], acc[mi][ni], 0, 0, 0);
    }
  }
#pragma unroll
  for (int mi = 0; mi < 4; ++mi) {
    int rowb = m0 + wmb + mi * 16 + (lane >> 4) * 4;
    float rb[4];
#pragma unroll
    for (int r = 0; r < 4; ++r) rb[r] = (BIASMODE == 2) ? bias[rowb + r] : 0.0f;
#pragma unroll
    for (int ni = 0; ni < 4; ++ni) {
      int col = n0 + wnb + ni * 16 + (lane & 15);
#pragma unroll
      for (int r = 0; r < 4; ++r) {
        float v = acc[mi][ni][r] + rb[r];
        if constexpr (F32OUT)
          ((float*)OutV)[(long)bz * ostr + (long)(rowb + r) * ldo + col] = v;
        else
          ((unsigned short*)OutV)[(long)bz * ostr + (long)(rowb + r) * ldo + col] = f2bf(v);
      }
    }
  }
}

// ------------------------------------------------------------------------------------
extern "C" void kernel_launch(void* const* d_in, const int* in_sizes, int n_in,
                              void* d_out, int out_size, void* d_ws, size_t ws_size,
                              hipStream_t stream) {
  (void)in_sizes; (void)n_in; (void)out_size; (void)ws_size;
  const float* x   = (const float*)d_in[0];
  const float* wq1 = (const float*)d_in[1];
  const float* bq1 = (const float*)d_in[2];
  const float* wk1 = (const float*)d_in[3];
  const float* bk1 = (const float*)d_in[4];
  const float* wq2 = (const float*)d_in[5];
  const float* bq2 = (const float*)d_in[6];
  const float* wk2 = (const float*)d_in[7];
  const float* bk2 = (const float*)d_in[8];
  const float* wq3 = (const float*)d_in[9];
  const float* bq3 = (const float*)d_in[10];
  const float* wk3 = (const float*)d_in[11];
  const float* bk3 = (const float*)d_in[12];
  const float* wv  = (const float*)d_in[13];
  const float* bv  = (const float*)d_in[14];
  const float* wo  = (const float*)d_in[15];
  const float* bo  = (const float*)d_in[16];
  char* ws = (char*)d_ws;

  // workspace layout (bytes), peak ~86 MB
  unsigned short* XT   = (unsigned short*)(ws + 0);         // [64][256][512] 16.8MB
  unsigned short* WQK1 = (unsigned short*)(ws + 16777216);  // [256][512]
  unsigned short* WQK2 = (unsigned short*)(ws + 17039360);  // [256][256]
  unsigned short* WQK3 = (unsigned short*)(ws + 17170432);  // [256][128]
  unsigned short* WOT  = (unsigned short*)(ws + 17235968);  // [512][512] wo^T
  unsigned short* WVNT = (unsigned short*)(ws + 17760256);  // [512][512] wv row-major
  unsigned short* WVOT = (unsigned short*)(ws + 18284544);  // [512][512] (wv@wo)^T
  float*          BVO  = (float*)(ws + 18808832);           // [512] bv@wo
  unsigned short* A1F  = (unsigned short*)(ws + 18876416);  // [64][4][256][64] frag
  unsigned short* A2F  = (unsigned short*)(ws + 27265024);  // [128][...] frag
  unsigned short* A3F  = (unsigned short*)(ws + 44042240);  // [256][...] frag
  unsigned short* ATTN = (unsigned short*)(ws + 77596672);  // [64][256][256] row-major
  unsigned short* XVT  = (unsigned short*)(ws + 18876416);  // over dead A1F/A2F (after gate)

  tcast_all<<<dim3(2296), dim3(256), 0, stream>>>(
      x, wq1, wk1, wq2, wk2, wq3, wk3, wv, wo,
      XT, WQK1, WQK2, WQK3, WVNT, WOT);

  projscore<<<dim3(1, 1, 468), dim3(1024), 131072, stream>>>(
      XT, WQK1, WQK2, WQK3, WOT, WVNT, WVOT, BVO, bv,
      A1F, A2F, A3F, bq1, bk1, bq2, bk2, bq3, bk3);

  gate_frag<<<dim3(2048), dim3(256), 0, stream>>>(A1F, A2F, A3F, ATTN);

  // XVT[b][p][d] = sum_s WVOT[p][s]*XT[b][d][s] + BVO[p]   (row-bias)
  gemm8<0, 2><<<dim3(2, 2, 64), dim3(512), 147456, stream>>>(
      WVOT, XT, XVT, BVO, 512, 512, 512, 0, 131072, 131072, 256);
  // out[b][p][c] = sum_d XVT[b][p][d]*ATTN[b][c][d] + bo[p] (row-bias, fp32)
  gemm8<1, 2><<<dim3(2, 2, 64), dim3(512), 147456, stream>>>(
      XVT, ATTN, d_out, bo, 256, 256, 256, 131072, 65536, 131072, 256);
}

// Round 20
// 91.778 us; speedup vs baseline: 1.0492x; 1.0492x over previous
//
#include <hip/hip_runtime.h>
#include <hip/hip_bf16.h>

// ChannelDeAttention: B=64,S=512,C=256,H=128,P=512
// bf16 MFMA (16x16x32), fp32 accum. 5 launches. XOR-swizzled LDS.
// R20 = R18 (best: fused proj+scores @1024thr, WVO fusion, 3-stage chain
// GEMMs) + hardware v_cvt_pk_bf16_f32 packing in hot bf16-convert paths.

typedef __attribute__((ext_vector_type(8))) short bf16x8;
typedef __attribute__((ext_vector_type(4))) float f32x4;
typedef __attribute__((ext_vector_type(8))) unsigned short ushort8;
typedef __attribute__((ext_vector_type(4))) unsigned int uint4v;

typedef __attribute__((address_space(1))) void* as1vp;
typedef __attribute__((address_space(3))) void* as3vp;

__device__ __forceinline__ void gl2lds16(const void* g, void* l) {
  __builtin_amdgcn_global_load_lds((as1vp)(void*)g, (as3vp)l, 16, 0, 0);
}

__device__ __forceinline__ float bf2f(unsigned short u) {
  union { unsigned int i; float f; } v; v.i = ((unsigned int)u) << 16; return v.f;
}
__device__ __forceinline__ unsigned short f2bf(float f) {
  union { float f; unsigned int i; } v; v.f = f;
  unsigned int r = v.i + 0x7FFFu + ((v.i >> 16) & 1u);
  return (unsigned short)(r >> 16);
}
// HW packed cvt: D[15:0]=bf16(a), D[31:16]=bf16(b)  (RNE, matches f2bf)
__device__ __forceinline__ unsigned int cvtpk(float a, float b) {
  unsigned int r;
  asm("v_cvt_pk_bf16_f32 %0, %1, %2" : "=v"(r) : "v"(a), "v"(b));
  return r;
}
__device__ __forceinline__ unsigned long long pack4pk(float a, float b, float c, float d) {
  return (unsigned long long)cvtpk(a, b) | ((unsigned long long)cvtpk(c, d) << 32);
}

// ------- transposes (x + 5 weight mats) + plain wv cast, one launch -----------------
__global__ void __launch_bounds__(256) tcast_all(
    const float* __restrict__ x,
    const float* __restrict__ wq1, const float* __restrict__ wk1,
    const float* __restrict__ wq2, const float* __restrict__ wk2,
    const float* __restrict__ wq3, const float* __restrict__ wk3,
    const float* __restrict__ wv, const float* __restrict__ wo,
    unsigned short* __restrict__ XT,
    unsigned short* __restrict__ W1, unsigned short* __restrict__ W2,
    unsigned short* __restrict__ W3, unsigned short* __restrict__ WVNT,
    unsigned short* __restrict__ WOT) {
  const int bid = blockIdx.x;
  const int t = threadIdx.x;
  if (bid >= 2168) {  // plain-cast wv to bf16 row-major (coalesced)
    long i0 = (long)(bid - 2168) * 2048 + t * 8;
    f32x4 a = *(const f32x4*)(wv + i0);
    f32x4 b = *(const f32x4*)(wv + i0 + 4);
    uint4v o = {cvtpk(a[0], a[1]), cvtpk(a[2], a[3]), cvtpk(b[0], b[1]), cvtpk(b[2], b[3])};
    *(uint4v*)(WVNT + i0) = o;
    return;
  }
  __shared__ float lds[64][68];
  const float* S; unsigned short* D; int R, Cc, r0, c0, rowoff = 0;
  if (bid < 2048) {
    int bz = bid >> 5, i = bid & 31;
    S = x + (long)bz * 131072; D = XT + (long)bz * 131072;
    R = 512; Cc = 256; r0 = (i & 7) * 64; c0 = (i >> 3) * 64;
  } else {
    int wb = bid - 2048;
    if (wb < 32) {
      int m = wb >> 4, i = wb & 15;
      S = m ? wk1 : wq1; D = W1; R = 512; Cc = 128;
      r0 = (i & 7) * 64; c0 = (i >> 3) * 64; rowoff = m * 128;
    } else if (wb < 48) {
      int m = (wb - 32) >> 3, i = (wb - 32) & 7;
      S = m ? wk2 : wq2; D = W2; R = 256; Cc = 128;
      r0 = (i & 3) * 64; c0 = (i >> 2) * 64; rowoff = m * 128;
    } else if (wb < 56) {
      int m = (wb - 48) >> 2, i = (wb - 48) & 3;
      S = m ? wk3 : wq3; D = W3; R = 128; Cc = 128;
      r0 = (i & 1) * 64; c0 = (i >> 1) * 64; rowoff = m * 128;
    } else {
      int i = wb - 56; S = wo; D = WOT; R = 512; Cc = 512;
      r0 = (i & 7) * 64; c0 = (i >> 3) * 64;
    }
  }
  {
    const int row = t >> 2, cq = (t & 3) * 16;
    const float* Sp = S + (long)(r0 + row) * Cc + c0 + cq;
#pragma unroll
    for (int j = 0; j < 4; ++j)
      *(f32x4*)&lds[row][cq + j * 4] = *(const f32x4*)(Sp + j * 4);
  }
  __syncthreads();
  {
    const int rq = (t & 15) * 4, ccb = t >> 4;
#pragma unroll
    for (int j = 0; j < 4; ++j) {
      int cc = ccb + j * 16;
      *(unsigned long long*)(D + (long)(c0 + cc + rowoff) * R + r0 + rq) =
          pack4pk(lds[rq][cc], lds[rq + 1][cc], lds[rq + 2][cc], lds[rq + 3][cc]);
    }
  }
}

// ------- FUSED proj + scores + softmax (+ WVOT + BVO blocks), 1024 threads ----------
// grid (1,1,468): z<448 fused sub-batch; z in [448,464) WVOT; z>=464 BVO.
__global__ void __launch_bounds__(1024) projscore(
    const unsigned short* __restrict__ XT,
    const unsigned short* __restrict__ W1, const unsigned short* __restrict__ W2,
    const unsigned short* __restrict__ W3,
    const unsigned short* __restrict__ WOT, const unsigned short* __restrict__ WVNT,
    unsigned short* __restrict__ WVOT, float* __restrict__ BVO,
    const float* __restrict__ bv,
    unsigned short* __restrict__ A1F, unsigned short* __restrict__ A2F,
    unsigned short* __restrict__ A3F,
    const float* __restrict__ bq1, const float* __restrict__ bk1,
    const float* __restrict__ bq2, const float* __restrict__ bk2,
    const float* __restrict__ bq3, const float* __restrict__ bk3) {
  extern __shared__ char smem[];
  const int z = blockIdx.z;
  const int t = threadIdx.x, lane = t & 63, wid = t >> 6;  // wid 0..15

  if (z >= 464) {  // ---- BVO[p] = sum_s bv[s] * WOT[p][s]; 16 waves x 8 p
    int p0 = (z - 464) * 128 + wid * 8;
    f32x4 b0 = *(const f32x4*)(bv + lane * 8);
    f32x4 b1 = *(const f32x4*)(bv + lane * 8 + 4);
#pragma unroll
    for (int i = 0; i < 8; ++i) {
      int p = p0 + i;
      bf16x8 wrow = *(const bf16x8*)(WOT + (long)p * 512 + lane * 8);
      float s = 0.0f;
#pragma unroll
      for (int j = 0; j < 4; ++j) {
        s += b0[j] * bf2f((unsigned short)wrow[j]);
        s += b1[j] * bf2f((unsigned short)wrow[4 + j]);
      }
#pragma unroll
      for (int off = 1; off < 64; off <<= 1) s += __shfl_xor(s, off, 64);
      if (lane == 0) BVO[p] = s;
    }
    return;
  }

  const int rS = t >> 3, sS = t & 7;  // 128 rows x 8 slots

  if (z >= 448) {  // ---- WVOT[p][s], SQ128 tile, 16 waves (32x32 wave-tile), single-buf
    const int w = z - 448;
    const int m0 = (w >> 2) * 128, n0 = (w & 3) * 128;
    const unsigned short* Ab = WOT + (long)m0 * 512;
    const unsigned short* Bb = WVNT + (long)n0 * 512;
    const int wmb = (wid >> 2) * 32, wnb = (wid & 3) * 32;
    f32x4 acc[2][2] = {};
    for (int k0 = 0; k0 < 512; k0 += 64) {
      int sc = (sS ^ (rS & 7)) * 8;
      gl2lds16(Ab + (long)rS * 512 + k0 + sc, smem + t * 16);
      gl2lds16(Bb + (long)rS * 512 + k0 + sc, smem + 16384 + t * 16);
      __syncthreads();
#pragma unroll
      for (int kk = 0; kk < 2; ++kk) {
        const int slot = kk * 4 + (lane >> 4);
        bf16x8 af[2], bfr[2];
#pragma unroll
        for (int mi = 0; mi < 2; ++mi) {
          int row = wmb + mi * 16 + (lane & 15);
          af[mi] = *(const bf16x8*)(smem + row * 128 + 16 * (slot ^ (row & 7)));
        }
#pragma unroll
        for (int ni = 0; ni < 2; ++ni) {
          int row = wnb + ni * 16 + (lane & 15);
          bfr[ni] = *(const bf16x8*)(smem + 16384 + row * 128 + 16 * (slot ^ (row & 7)));
        }
#pragma unroll
        for (int mi = 0; mi < 2; ++mi)
#pragma unroll
          for (int ni = 0; ni < 2; ++ni)
            acc[mi][ni] = __builtin_amdgcn_mfma_f32_16x16x32_bf16(af[mi], bfr[ni], acc[mi][ni], 0, 0, 0);
      }
      __syncthreads();
    }
#pragma unroll
    for (int ni = 0; ni < 2; ++ni) {
      int col = n0 + wnb + ni * 16 + (lane & 15);
#pragma unroll
      for (int mi = 0; mi < 2; ++mi) {
        int rowb = m0 + wmb + mi * 16 + (lane >> 4) * 4;
#pragma unroll
        for (int r = 0; r < 4; ++r)
          WVOT[(long)(rowb + r) * 512 + col] = f2bf(acc[mi][ni][r]);
      }
    }
    return;
  }

  // ---- fused path: GEMM (BM=256 channels x BN=256 q|k), 64x64 wave-tiles ----
  const unsigned short* Ab; const unsigned short* Bw; unsigned short* AF;
  const float *bq, *bk; int K; long sb;
  if (z < 64) {
    K = 512; Bw = W1; AF = A1F; sb = z; bq = bq1; bk = bk1;
    Ab = XT + (long)z * 131072;
  } else if (z < 192) {
    int u = z - 64; K = 256; Bw = W2; AF = A2F; sb = u; bq = bq2; bk = bk2;
    Ab = XT + (long)(u >> 1) * 131072 + (u & 1) * 256;
  } else {
    int u = z - 192; K = 128; Bw = W3; AF = A3F; sb = u; bq = bq3; bk = bk3;
    Ab = XT + (long)(u >> 2) * 131072 + (u & 3) * 128;
  }
  const int wmb = (wid >> 2) * 64, wnb = (wid & 3) * 64;  // 4m x 4n waves

  auto stage = [&](int buf, int k0) {  // 4 loads/thread: A[256][64]sw + B[256][64]sw
    char* s = smem + buf * 65536;
#pragma unroll
    for (int i = 0; i < 2; ++i) {
      int row = i * 128 + rS;
      int sc = (sS ^ (row & 7)) * 8;
      gl2lds16(Ab + (long)row * 512 + k0 + sc, s + i * 16384 + t * 16);
      gl2lds16(Bw + (long)row * K + k0 + sc, s + 32768 + i * 16384 + t * 16);
    }
  };

  f32x4 acc[4][4] = {};
  const int nst = K >> 6;
  stage(0, 0);
  __syncthreads();
  int cur = 0;
  for (int j = 0; j < nst; ++j) {
    if (j + 1 < nst) stage(cur ^ 1, (j + 1) * 64);
    const char* s = smem + cur * 65536;
#pragma unroll
    for (int kk = 0; kk < 2; ++kk) {
      const int slot = kk * 4 + (lane >> 4);
      bf16x8 af[4], bfr[4];
#pragma unroll
      for (int mi = 0; mi < 4; ++mi) {
        int row = wmb + mi * 16 + (lane & 15);
        af[mi] = *(const bf16x8*)(s + row * 128 + 16 * (slot ^ (row & 7)));
      }
#pragma unroll
      for (int ni = 0; ni < 4; ++ni) {
        int row = wnb + ni * 16 + (lane & 15);
        bfr[ni] = *(const bf16x8*)(s + 32768 + row * 128 + 16 * (slot ^ (row & 7)));
      }
      // swapped operands: lane holds 4 consecutive out-cols per fragment
#pragma unroll
      for (int mi = 0; mi < 4; ++mi)
#pragma unroll
        for (int ni = 0; ni < 4; ++ni)
          acc[mi][ni] = __builtin_amdgcn_mfma_f32_16x16x32_bf16(bfr[ni], af[mi], acc[mi][ni], 0, 0, 0);
    }
    __syncthreads();
    cur ^= 1;
  }

  // write q/k into swizzled LDS: q @ [2chunks][256][64] at 0, k at 65536
  {
    const int chB = (wnb < 128) ? 0 : 65536;
    const float* bias = (wnb < 128) ? bq : bk;
    const int hbase = wnb & 127;
#pragma unroll
    for (int mi = 0; mi < 4; ++mi) {
      int rowm = wmb + mi * 16 + (lane & 15);
#pragma unroll
      for (int ni = 0; ni < 4; ++ni) {
        int h = hbase + ni * 16 + (lane >> 4) * 4;
        int addr = chB + (h >> 6) * 32768 + rowm * 128 +
                   16 * (((h & 63) >> 3) ^ (rowm & 7)) + (h & 7) * 2;
        *(unsigned long long*)(smem + addr) =
            pack4pk(acc[mi][ni][0] + bias[h], acc[mi][ni][1] + bias[h + 1],
                    acc[mi][ni][2] + bias[h + 2], acc[mi][ni][3] + bias[h + 3]);
      }
    }
  }
  __syncthreads();

  // scores: S = q k^T, wave w -> q-rows [w*16, w*16+16)
  f32x4 acc2[16] = {};
  const int qrow = wid * 16 + (lane & 15);
#pragma unroll
  for (int kc = 0; kc < 2; ++kc)
#pragma unroll
    for (int kk = 0; kk < 2; ++kk) {
      const int slot = kk * 4 + (lane >> 4);
      bf16x8 qf = *(const bf16x8*)(smem + kc * 32768 + qrow * 128 + 16 * (slot ^ (qrow & 7)));
#pragma unroll
      for (int ni = 0; ni < 16; ++ni) {
        int krow = ni * 16 + (lane & 15);
        bf16x8 kf = *(const bf16x8*)(smem + 65536 + kc * 32768 + krow * 128 + 16 * (slot ^ (krow & 7)));
        acc2[ni] = __builtin_amdgcn_mfma_f32_16x16x32_bf16(qf, kf, acc2[ni], 0, 0, 0);
      }
    }

  const float sc = 0.088388347648318447f;  // 1/sqrt(128)
  {
    int m0idx = wid >> 2, quad = wid & 3;
    unsigned short* Of = AF + ((sb * 4 + m0idx) * 256 + quad * 64 + lane) * 64;
#pragma unroll
    for (int r = 0; r < 4; ++r) {
      float mx = -1e30f;
#pragma unroll
      for (int ni = 0; ni < 16; ++ni) mx = fmaxf(mx, acc2[ni][r]);
#pragma unroll
      for (int off = 1; off < 16; off <<= 1) mx = fmaxf(mx, __shfl_xor(mx, off, 64));
      float s = 0.0f;
      float p[16];
#pragma unroll
      for (int ni = 0; ni < 16; ++ni) {
        p[ni] = __expf((acc2[ni][r] - mx) * sc);
        s += p[ni];
      }
#pragma unroll
      for (int off = 1; off < 16; off <<= 1) s += __shfl_xor(s, off, 64);
      float inv = 1.0f / s;
      uint4v wlo = {cvtpk(p[0] * inv, p[1] * inv), cvtpk(p[2] * inv, p[3] * inv),
                    cvtpk(p[4] * inv, p[5] * inv), cvtpk(p[6] * inv, p[7] * inv)};
      uint4v whi = {cvtpk(p[8] * inv, p[9] * inv), cvtpk(p[10] * inv, p[11] * inv),
                    cvtpk(p[12] * inv, p[13] * inv), cvtpk(p[14] * inv, p[15] * inv)};
      *(uint4v*)(Of + r * 16) = wlo;
      *(uint4v*)(Of + r * 16 + 8) = whi;
    }
  }
}

// ------- gate: flat elementwise in fragment space, coalesced reads ------------------
__global__ void __launch_bounds__(256) gate_frag(
    const unsigned short* __restrict__ A1F, const unsigned short* __restrict__ A2F,
    const unsigned short* __restrict__ A3F, unsigned short* __restrict__ ATTN) {
  const long gid = (long)blockIdx.x * 256 + threadIdx.x;
  const long i = gid * 8;
  const int b = (int)(i >> 16);
  const int rest = (int)(i & 65535);
  ushort8 a1 = *(const ushort8*)(A1F + i);
  const long i2 = ((long)(2 * b) << 16) + rest;
  ushort8 a2a = *(const ushort8*)(A2F + i2);
  ushort8 a2b = *(const ushort8*)(A2F + i2 + 65536);
  const long i3 = ((long)(4 * b) << 16) + rest;
  ushort8 a3a = *(const ushort8*)(A3F + i3);
  ushort8 a3b = *(const ushort8*)(A3F + i3 + 65536);
  ushort8 a3c = *(const ushort8*)(A3F + i3 + 131072);
  ushort8 a3d = *(const ushort8*)(A3F + i3 + 196608);
  const int f = rest & 63;
  const int tl = (rest >> 6) & 255;
  const int m0idx = rest >> 14;
  const int quad = (tl >> 6) & 3;
  const int lane_s = tl & 63;
  const int r = f >> 4;
  const int u0 = f & 15;  // 0 or 8
  const int row = m0idx * 64 + quad * 16 + (lane_s >> 4) * 4 + r;
  unsigned short* Orow = ATTN + ((long)b << 16) + (long)row * 256 + (lane_s & 15);
#pragma unroll
  for (int j = 0; j < 8; ++j) {
    float A1 = bf2f(a1[j]);
    float A2 = 0.5f * (bf2f(a2a[j]) + bf2f(a2b[j]));
    float A3 = 0.25f * (bf2f(a3a[j]) + bf2f(a3b[j]) + bf2f(a3c[j]) + bf2f(a3d[j]));
    float m = fmaxf(A1, fmaxf(A2, A3));
    float e1 = __expf(A1 - m), e2 = __expf(A2 - m), e3 = __expf(A3 - m);
    Orow[(u0 + j) * 16] = f2bf((A1 * e1 + A2 * e2 + A3 * e3) / (e1 + e2 + e3));
  }
}

// ------- 8-wave TALL(256x128) NT GEMM, 3-stage pipeline, counted vmcnt (R16) --------
template <int F32OUT, int BIASMODE>
__global__ void __launch_bounds__(512) gemm8(
    const unsigned short* __restrict__ A, const unsigned short* __restrict__ B,
    void* __restrict__ OutV, const float* __restrict__ bias,
    int lda, int ldb, int K, long astr, long bstr, long ostr, int ldo) {
  extern __shared__ char smem[];  // per buf 48K: A [256][64]sw + B [128][64]sw
  const int t = threadIdx.x, lane = t & 63, wid = t >> 6;
  const int wmb = (wid >> 1) * 64, wnb = (wid & 1) * 64;
  const int m0 = blockIdx.y * 256, n0 = blockIdx.x * 128;
  const int bz = blockIdx.z;
  const unsigned short* Ab = A + (long)bz * astr + (long)m0 * lda;
  const unsigned short* Bb = B + (long)bz * bstr + (long)n0 * ldb;
  const int srow = t >> 3, ssl = t & 7;

  auto stage = [&](int buf, int k0) {  // 6 loads/thread
    char* s = smem + buf * 49152;
#pragma unroll
    for (int i = 0; i < 4; ++i) {
      int row = i * 64 + srow;
      gl2lds16(Ab + (long)row * lda + k0 + (ssl ^ (row & 7)) * 8, s + i * 8192 + t * 16);
    }
#pragma unroll
    for (int i = 0; i < 2; ++i) {
      int row = i * 64 + srow;
      gl2lds16(Bb + (long)row * ldb + k0 + (ssl ^ (row & 7)) * 8,
               s + 32768 + i * 8192 + t * 16);
    }
  };

  f32x4 acc[4][4] = {};
  const int nst = K >> 6;
  stage(0, 0);
  stage(1, 64);
  for (int j = 0; j < nst; ++j) {
    if (j + 1 < nst) asm volatile("s_waitcnt vmcnt(6)" ::: "memory");
    else             asm volatile("s_waitcnt vmcnt(0)" ::: "memory");
    __builtin_amdgcn_s_barrier();
    if (j + 2 < nst) stage((j + 2) % 3, (j + 2) * 64);
    const char* s = smem + (j % 3) * 49152;
#pragma unroll
    for (int kk = 0; kk < 2; ++kk) {
      const int slot = kk * 4 + (lane >> 4);
      bf16x8 af[4], bfr[4];
#pragma unroll
      for (int mi = 0; mi < 4; ++mi) {
        int row = wmb + mi * 16 + (lane & 15);
        af[mi] = *(const bf16x8*)(s + row * 128 + 16 * (slot ^ (row & 7)));
      }
#pragma unroll
      for (int ni = 0; ni < 4; ++ni) {
        int row = wnb + ni * 16 + (lane & 15);
        bfr[ni] = *(const bf16x8*)(s + 32768 + row * 128 + 16 * (slot ^ (row & 7)));
      }
#pragma unroll
      for (int mi = 0; mi < 4; ++mi)
#pragma unroll
        for (int ni = 0; ni < 4; ++ni)
          acc[mi][ni] = __builtin_amdgcn_mfma_f32_16x16x32_bf16(af[mi], bfr[ni], acc[mi][ni], 0, 0, 0);
    }
  }
#pragma unroll
  for (int mi = 0; mi < 4; ++mi) {
    int rowb = m0 + wmb + mi * 16 + (lane >> 4) * 4;
    float rb[4];
#pragma unroll
    for (int r = 0; r < 4; ++r) rb[r] = (BIASMODE == 2) ? bias[rowb + r] : 0.0f;
#pragma unroll
    for (int ni = 0; ni < 4; ++ni) {
      int col = n0 + wnb + ni * 16 + (lane & 15);
#pragma unroll
      for (int r = 0; r < 4; ++r) {
        float v = acc[mi][ni][r] + rb[r];
        if constexpr (F32OUT)
          ((float*)OutV)[(long)bz * ostr + (long)(rowb + r) * ldo + col] = v;
        else
          ((unsigned short*)OutV)[(long)bz * ostr + (long)(rowb + r) * ldo + col] = f2bf(v);
      }
    }
  }
}

// ------------------------------------------------------------------------------------
extern "C" void kernel_launch(void* const* d_in, const int* in_sizes, int n_in,
                              void* d_out, int out_size, void* d_ws, size_t ws_size,
                              hipStream_t stream) {
  (void)in_sizes; (void)n_in; (void)out_size; (void)ws_size;
  const float* x   = (const float*)d_in[0];
  const float* wq1 = (const float*)d_in[1];
  const float* bq1 = (const float*)d_in[2];
  const float* wk1 = (const float*)d_in[3];
  const float* bk1 = (const float*)d_in[4];
  const float* wq2 = (const float*)d_in[5];
  const float* bq2 = (const float*)d_in[6];
  const float* wk2 = (const float*)d_in[7];
  const float* bk2 = (const float*)d_in[8];
  const float* wq3 = (const float*)d_in[9];
  const float* bq3 = (const float*)d_in[10];
  const float* wk3 = (const float*)d_in[11];
  const float* bk3 = (const float*)d_in[12];
  const float* wv  = (const float*)d_in[13];
  const float* bv  = (const float*)d_in[14];
  const float* wo  = (const float*)d_in[15];
  const float* bo  = (const float*)d_in[16];
  char* ws = (char*)d_ws;

  // workspace layout (bytes), peak ~86 MB
  unsigned short* XT   = (unsigned short*)(ws + 0);         // [64][256][512] 16.8MB
  unsigned short* WQK1 = (unsigned short*)(ws + 16777216);  // [256][512]
  unsigned short* WQK2 = (unsigned short*)(ws + 17039360);  // [256][256]
  unsigned short* WQK3 = (unsigned short*)(ws + 17170432);  // [256][128]
  unsigned short* WOT  = (unsigned short*)(ws + 17235968);  // [512][512] wo^T
  unsigned short* WVNT = (unsigned short*)(ws + 17760256);  // [512][512] wv row-major
  unsigned short* WVOT = (unsigned short*)(ws + 18284544);  // [512][512] (wv@wo)^T
  float*          BVO  = (float*)(ws + 18808832);           // [512] bv@wo
  unsigned short* A1F  = (unsigned short*)(ws + 18876416);  // [64][4][256][64] frag
  unsigned short* A2F  = (unsigned short*)(ws + 27265024);  // [128][...] frag
  unsigned short* A3F  = (unsigned short*)(ws + 44042240);  // [256][...] frag
  unsigned short* ATTN = (unsigned short*)(ws + 77596672);  // [64][256][256] row-major
  unsigned short* XVT  = (unsigned short*)(ws + 18876416);  // over dead A1F/A2F (after gate)

  tcast_all<<<dim3(2296), dim3(256), 0, stream>>>(
      x, wq1, wk1, wq2, wk2, wq3, wk3, wv, wo,
      XT, WQK1, WQK2, WQK3, WVNT, WOT);

  projscore<<<dim3(1, 1, 468), dim3(1024), 131072, stream>>>(
      XT, WQK1, WQK2, WQK3, WOT, WVNT, WVOT, BVO, bv,
      A1F, A2F, A3F, bq1, bk1, bq2, bk2, bq3, bk3);

  gate_frag<<<dim3(2048), dim3(256), 0, stream>>>(A1F, A2F, A3F, ATTN);

  // XVT[b][p][d] = sum_s WVOT[p][s]*XT[b][d][s] + BVO[p]   (row-bias)
  gemm8<0, 2><<<dim3(2, 2, 64), dim3(512), 147456, stream>>>(
      WVOT, XT, XVT, BVO, 512, 512, 512, 0, 131072, 131072, 256);
  // out[b][p][c] = sum_d XVT[b][p][d]*ATTN[b][c][d] + bo[p] (row-bias, fp32)
  gemm8<1, 2><<<dim3(2, 2, 64), dim3(512), 147456, stream>>>(
      XVT, ATTN, d_out, bo, 256, 256, 256, 131072, 65536, 131072, 256);
}